// Round 1
// baseline (612.437 us; speedup 1.0000x reference)
//
#include <hip/hip_runtime.h>
#include <math.h>

#define BLK 256

constexpr int Bg    = 2048;
constexpr int Fn    = 64;          // nodes per graph
constexpr int DIN   = 32;
constexpr int Hd    = 128;
constexpr int HEADS = 4;
constexpr int NC    = 16;
constexpr int EPG   = 128;
constexpr int Etot  = Bg * EPG;    // 262144
constexpr int HSTR  = 132;         // LDS row stride (floats); 132*4B = 528B, 16B-aligned
constexpr int W1C   = HEADS * Hd;  // 512

// Precomputed fused aligner: Wc = W_align @ W1 (32x512), c1 = b_align @ W1 (512)
__device__ float g_wcomb[DIN * W1C];
__device__ float g_c1[W1C];

__global__ __launch_bounds__(BLK) void prep_kernel(
    const float* __restrict__ Wa, const float* __restrict__ ba,
    const float* __restrict__ W1)
{
  int i = blockIdx.x * BLK + threadIdx.x;
  if (i < DIN * W1C) {
    int k = i >> 9, c = i & 511;
    float a = 0.f;
    for (int m = 0; m < Hd; ++m) a += Wa[k*Hd + m] * W1[m*W1C + c];
    g_wcomb[i] = a;
  } else if (i < DIN*W1C + W1C) {
    int c = i - DIN*W1C;
    float a = 0.f;
    for (int m = 0; m < Hd; ++m) a += ba[m] * W1[m*W1C + c];
    g_c1[c] = a;
  }
}

__global__ __launch_bounds__(BLK) void gat_main(
    const float* __restrict__ emb, const int* __restrict__ ei,
    const float* __restrict__ gate_logits,
    const float* __restrict__ a_src1, const float* __restrict__ a_dst1,
    const float* __restrict__ b1,
    const float* __restrict__ W2,
    const float* __restrict__ a_src2, const float* __restrict__ a_dst2,
    const float* __restrict__ b2,
    const float* __restrict__ Wc1, const float* __restrict__ bc1,
    const float* __restrict__ Wc2, const float* __restrict__ bc2,
    float* __restrict__ out)
{
  __shared__ __align__(16) float hS[Fn * HSTR];     // 33792 B: per-head h / elu / h2
  __shared__ __align__(16) float embS[Fn * DIN];    // 8192 B
  __shared__ float sSrc[Fn], sDst[Fn], sInv[Fn], gateS[Fn];
  __shared__ float alphaS[EPG + Fn];                // 192 edges incl self-loops
  __shared__ unsigned short colS[EPG + Fn];
  __shared__ unsigned short rowptr[Fn + 1];
  __shared__ unsigned int degS[Fn], cntS[Fn];
  __shared__ float gpool[Hd];
  __shared__ float hcS[Fn];

  const int b    = blockIdx.x;
  const int tid  = threadIdx.x;
  const int lane = tid & 63;
  const int wv   = tid >> 6;
  const int nodeBase = wv * 16;      // GEMM mapping: wave owns 16 nodes
  const int d0   = lane * 2;         // each lane owns 2 output dims
  const int tt   = tid >> 2;         // attention mapping: 4 threads per target
  const int jj   = tid & 3;          // 32-dim quarter

  // ---- stage emb tile, gate, CSR build ----
  const float* embG = emb + (size_t)b * Fn * DIN;
  for (int i = tid; i < Fn * DIN; i += BLK) embS[i] = embG[i];
  if (tid < Fn) {
    float g = 1.f / (1.f + expf(-gate_logits[tid]));
    gateS[tid] = g;
    degS[tid] = 0; cntS[tid] = 0;
    if (b == 0) out[Bg*NC + tid] = g;            // gate output (second tuple element)
  }
  __syncthreads();

  const int* srcG = ei + (size_t)b * EPG;
  const int* tgtG = ei + (size_t)Etot + (size_t)b * EPG;
  const int base  = b * Fn;
  if (tid < EPG) {
    int t = tgtG[tid] - base;
    atomicAdd(&degS[t], 1u);
  } else if (tid < EPG + Fn) {
    atomicAdd(&degS[tid - EPG], 1u);             // self-loop
  }
  __syncthreads();
  if (tid == 0) {
    unsigned acc = 0;
    for (int i = 0; i < Fn; ++i) { rowptr[i] = (unsigned short)acc; acc += degS[i]; }
    rowptr[Fn] = (unsigned short)acc;            // == 192
  }
  __syncthreads();
  if (tid < EPG) {
    int s = srcG[tid] - base, t = tgtG[tid] - base;
    unsigned p = rowptr[t] + atomicAdd(&cntS[t], 1u);
    colS[p] = (unsigned short)s;
  } else if (tid < EPG + Fn) {
    int t = tid - EPG;
    unsigned p = rowptr[t] + atomicAdd(&cntS[t], 1u);
    colS[p] = (unsigned short)t;
  }

  float h2a[32];                                  // persistent GEMM2 accumulator
  #pragma unroll
  for (int i = 0; i < 32; ++i) h2a[i] = 0.f;
  __syncthreads();

  // ---- per-head: GEMM1 -> attention -> +b1,ELU -> GEMM2-accumulate ----
  for (int hh = 0; hh < HEADS; ++hh) {
    {   // GEMM1: h[n][d] = gate[n] * (emb[n] @ g_wcomb[:, hh*128+d] + g_c1[hh*128+d])
      const float* wc = g_wcomb + hh * Hd;
      float acc[32];
      const float cc0 = g_c1[hh*Hd + d0];
      const float cc1 = g_c1[hh*Hd + d0 + 1];
      #pragma unroll
      for (int nn = 0; nn < 16; ++nn) { acc[2*nn] = cc0; acc[2*nn+1] = cc1; }
      #pragma unroll
      for (int kc = 0; kc < 4; ++kc) {
        float wr[16];
        #pragma unroll
        for (int kk = 0; kk < 8; ++kk) {
          const float2 w = *(const float2*)&wc[(kc*8 + kk) * W1C + d0];
          wr[2*kk] = w.x; wr[2*kk+1] = w.y;
        }
        #pragma unroll
        for (int nn = 0; nn < 16; ++nn) {
          const float* er = &embS[(nodeBase + nn) * DIN + kc*8];
          float4 e0 = *(const float4*)&er[0];
          float4 e1 = *(const float4*)&er[4];
          acc[2*nn]   += e0.x*wr[0] + e0.y*wr[2] + e0.z*wr[4] + e0.w*wr[6]
                       + e1.x*wr[8] + e1.y*wr[10]+ e1.z*wr[12]+ e1.w*wr[14];
          acc[2*nn+1] += e0.x*wr[1] + e0.y*wr[3] + e0.z*wr[5] + e0.w*wr[7]
                       + e1.x*wr[9] + e1.y*wr[11]+ e1.z*wr[13]+ e1.w*wr[15];
        }
      }
      #pragma unroll
      for (int nn = 0; nn < 16; ++nn) {
        const float g = gateS[nodeBase + nn];
        float2 v; v.x = acc[2*nn]*g; v.y = acc[2*nn+1]*g;
        *(float2*)&hS[(nodeBase + nn)*HSTR + d0] = v;
      }
    }
    __syncthreads();

    {   // attention scores s_src/s_dst (dot of h row with a-vectors)
      const float* asp = a_src1 + hh*Hd + jj*32;
      const float* adp = a_dst1 + hh*Hd + jj*32;
      const float* hr  = &hS[tt*HSTR + jj*32];
      float ps = 0.f, pd = 0.f;
      #pragma unroll
      for (int i = 0; i < 32; i += 4) {
        float4 hv = *(const float4*)&hr[i];
        float4 av = *(const float4*)&asp[i];
        float4 dv = *(const float4*)&adp[i];
        ps += hv.x*av.x + hv.y*av.y + hv.z*av.z + hv.w*av.w;
        pd += hv.x*dv.x + hv.y*dv.y + hv.z*dv.z + hv.w*dv.w;
      }
      ps += __shfl_xor(ps, 1); ps += __shfl_xor(ps, 2);
      pd += __shfl_xor(pd, 1); pd += __shfl_xor(pd, 2);
      if (jj == 0) { sSrc[tt] = ps; sDst[tt] = pd; }
    }
    __syncthreads();

    // per-target softmax (leaky 0.2, max, exp, sum)
    if (tid < Fn) {
      const int r0 = rowptr[tid], r1 = rowptr[tid + 1];
      const float sd = sDst[tid];
      float m = -1e30f;
      for (int p = r0; p < r1; ++p) {
        float e = sSrc[colS[p]] + sd;
        e = (e > 0.f) ? e : 0.2f * e;
        alphaS[p] = e;
        m = fmaxf(m, e);
      }
      float ss = 0.f;
      for (int p = r0; p < r1; ++p) {
        float pe = expf(alphaS[p] - m);
        alphaS[p] = pe; ss += pe;
      }
      sInv[tid] = 1.f / (ss + 1e-16f);
    }
    __syncthreads();

    // weighted gather: out[t] = (1/ssum) * sum_e p_e * h[src_e]
    float oacc[32];
    #pragma unroll
    for (int i = 0; i < 32; ++i) oacc[i] = 0.f;
    {
      const int r0 = rowptr[tt], r1 = rowptr[tt + 1];
      for (int p = r0; p < r1; ++p) {
        const float al = alphaS[p];
        const float* hsrow = &hS[(int)colS[p]*HSTR + jj*32];
        #pragma unroll
        for (int i = 0; i < 32; i += 4) {
          float4 v = *(const float4*)&hsrow[i];
          oacc[i]   += al * v.x;
          oacc[i+1] += al * v.y;
          oacc[i+2] += al * v.z;
          oacc[i+3] += al * v.w;
        }
      }
    }
    __syncthreads();   // all reads of hS done before overwrite
    {   // +b1, ELU, write back into hS
      const float si = sInv[tt];
      const float* bb = b1 + hh*Hd + jj*32;
      float* hw = &hS[tt*HSTR + jj*32];
      #pragma unroll
      for (int i = 0; i < 32; i += 4) {
        float4 bv = *(const float4*)&bb[i];
        float v0 = oacc[i]  *si + bv.x;
        float v1 = oacc[i+1]*si + bv.y;
        float v2 = oacc[i+2]*si + bv.z;
        float v3 = oacc[i+3]*si + bv.w;
        v0 = v0 > 0.f ? v0 : expm1f(v0);
        v1 = v1 > 0.f ? v1 : expm1f(v1);
        v2 = v2 > 0.f ? v2 : expm1f(v2);
        v3 = v3 > 0.f ? v3 : expm1f(v3);
        float4 w; w.x=v0; w.y=v1; w.z=v2; w.w=v3;
        *(float4*)&hw[i] = w;
      }
    }
    __syncthreads();

    {   // GEMM2-accumulate: h2a[n][d] += elu[n][k] * W2[hh*128+k][d]
      const float* w2h = W2 + (size_t)(hh*Hd) * Hd;
      for (int kc = 0; kc < 16; ++kc) {
        float wr[16];
        #pragma unroll
        for (int kk = 0; kk < 8; ++kk) {
          const float2 w = *(const float2*)&w2h[(kc*8 + kk)*Hd + d0];
          wr[2*kk] = w.x; wr[2*kk+1] = w.y;
        }
        #pragma unroll
        for (int nn = 0; nn < 16; ++nn) {
          const float* er = &hS[(nodeBase + nn)*HSTR + kc*8];
          float4 e0 = *(const float4*)&er[0];
          float4 e1 = *(const float4*)&er[4];
          h2a[2*nn]   += e0.x*wr[0] + e0.y*wr[2] + e0.z*wr[4] + e0.w*wr[6]
                       + e1.x*wr[8] + e1.y*wr[10]+ e1.z*wr[12]+ e1.w*wr[14];
          h2a[2*nn+1] += e0.x*wr[1] + e0.y*wr[3] + e0.z*wr[5] + e0.w*wr[7]
                       + e1.x*wr[9] + e1.y*wr[11]+ e1.z*wr[13]+ e1.w*wr[15];
        }
      }
    }
    __syncthreads();   // before next head overwrites hS
  }

  // ---- publish h2 to LDS ----
  #pragma unroll
  for (int nn = 0; nn < 16; ++nn) {
    float2 v; v.x = h2a[2*nn]; v.y = h2a[2*nn+1];
    *(float2*)&hS[(nodeBase + nn)*HSTR + d0] = v;
  }
  __syncthreads();

  // ---- layer-2 attention (1 head) ----
  {
    const float* asp = a_src2 + jj*32;
    const float* adp = a_dst2 + jj*32;
    const float* hr  = &hS[tt*HSTR + jj*32];
    float ps = 0.f, pd = 0.f;
    #pragma unroll
    for (int i = 0; i < 32; i += 4) {
      float4 hv = *(const float4*)&hr[i];
      float4 av = *(const float4*)&asp[i];
      float4 dv = *(const float4*)&adp[i];
      ps += hv.x*av.x + hv.y*av.y + hv.z*av.z + hv.w*av.w;
      pd += hv.x*dv.x + hv.y*dv.y + hv.z*dv.z + hv.w*dv.w;
    }
    ps += __shfl_xor(ps, 1); ps += __shfl_xor(ps, 2);
    pd += __shfl_xor(pd, 1); pd += __shfl_xor(pd, 2);
    if (jj == 0) { sSrc[tt] = ps; sDst[tt] = pd; }
  }
  __syncthreads();
  if (tid < Fn) {
    const int r0 = rowptr[tid], r1 = rowptr[tid + 1];
    const float sd = sDst[tid];
    float m = -1e30f;
    for (int p = r0; p < r1; ++p) {
      float e = sSrc[colS[p]] + sd;
      e = (e > 0.f) ? e : 0.2f * e;
      alphaS[p] = e;
      m = fmaxf(m, e);
    }
    float ss = 0.f;
    for (int p = r0; p < r1; ++p) {
      float pe = expf(alphaS[p] - m);
      alphaS[p] = pe; ss += pe;
    }
    sInv[tid] = 1.f / (ss + 1e-16f);
  }
  __syncthreads();
  {
    float oacc[32];
    #pragma unroll
    for (int i = 0; i < 32; ++i) oacc[i] = 0.f;
    const int r0 = rowptr[tt], r1 = rowptr[tt + 1];
    for (int p = r0; p < r1; ++p) {
      const float al = alphaS[p];
      const float* hsrow = &hS[(int)colS[p]*HSTR + jj*32];
      #pragma unroll
      for (int i = 0; i < 32; i += 4) {
        float4 v = *(const float4*)&hsrow[i];
        oacc[i]   += al * v.x;
        oacc[i+1] += al * v.y;
        oacc[i+2] += al * v.z;
        oacc[i+3] += al * v.w;
      }
    }
    __syncthreads();   // all reads of hS done
    const float si = sInv[tt];
    const float* bb = b2 + jj*32;
    float* hw = &hS[tt*HSTR + jj*32];
    #pragma unroll
    for (int i = 0; i < 32; i += 4) {
      float4 bv = *(const float4*)&bb[i];
      float4 w;
      w.x = oacc[i]  *si + bv.x;
      w.y = oacc[i+1]*si + bv.y;
      w.z = oacc[i+2]*si + bv.z;
      w.w = oacc[i+3]*si + bv.w;
      *(float4*)&hw[i] = w;
    }
  }
  __syncthreads();

  // ---- global mean pool ----
  if (tid < Hd) {
    float s = 0.f;
    for (int n = 0; n < Fn; ++n) s += hS[n*HSTR + tid];
    gpool[tid] = s * (1.f / 64.f);
  }
  __syncthreads();

  // ---- classifier MLP ----
  if (tid < Fn) {
    float a = bc1[tid];
    for (int k = 0; k < Hd; ++k) a += gpool[k] * Wc1[k*Fn + tid];
    hcS[tid] = a > 0.f ? a : 0.01f * a;
  }
  __syncthreads();
  if (tid < NC) {
    float a = bc2[tid];
    for (int k = 0; k < Fn; ++k) a += hcS[k] * Wc2[k*NC + tid];
    out[b*NC + tid] = a;
  }
}

extern "C" void kernel_launch(void* const* d_in, const int* in_sizes, int n_in,
                              void* d_out, int out_size, void* d_ws, size_t ws_size,
                              hipStream_t stream) {
  const float* emb = (const float*)d_in[0];
  const int*   ei  = (const int*)  d_in[1];
  // d_in[2] = batch_idx (unused: layout is known)
  const float* Wa  = (const float*)d_in[3];
  const float* ba  = (const float*)d_in[4];
  const float* gl  = (const float*)d_in[5];
  const float* W1  = (const float*)d_in[6];
  const float* as1 = (const float*)d_in[7];
  const float* ad1 = (const float*)d_in[8];
  const float* b1  = (const float*)d_in[9];
  const float* W2  = (const float*)d_in[10];
  const float* as2 = (const float*)d_in[11];
  const float* ad2 = (const float*)d_in[12];
  const float* b2  = (const float*)d_in[13];
  const float* Wc1 = (const float*)d_in[14];
  const float* bc1 = (const float*)d_in[15];
  const float* Wc2 = (const float*)d_in[16];
  const float* bc2 = (const float*)d_in[17];
  float* out = (float*)d_out;

  const int prepN = DIN*W1C + W1C;
  hipLaunchKernelGGL(prep_kernel, dim3((prepN + BLK - 1)/BLK), dim3(BLK), 0, stream,
                     Wa, ba, W1);
  hipLaunchKernelGGL(gat_main, dim3(Bg), dim3(BLK), 0, stream,
                     emb, ei, gl, as1, ad1, b1, W2, as2, ad2, b2,
                     Wc1, bc1, Wc2, bc2, out);
}

// Round 2
// 343.659 us; speedup vs baseline: 1.7821x; 1.7821x over previous
//
#include <hip/hip_runtime.h>
#include <math.h>

#define BLK 256

constexpr int Bg    = 2048;
constexpr int Fn    = 64;
constexpr int DIN   = 32;
constexpr int Hd    = 128;
constexpr int HEADS = 4;
constexpr int NC    = 16;
constexpr int EPG   = 128;
constexpr int Etot  = Bg * EPG;
constexpr int W1C   = HEADS * Hd;   // 512
constexpr int HROW  = 144;          // fp32 words per hS row: 4 skewed chunks of 36
constexpr int EROW  = 136;          // bf16 elems per eluS row (128 + 8 pad)

typedef __attribute__((ext_vector_type(8))) __bf16 bf16x8;
typedef __attribute__((ext_vector_type(4))) float  f32x4;

// Precomputed weights:
//   g_wcombT[n][k] = bf16( (W_align @ W1)[k][n] ), n<512, k<32   (B-operand layout, GEMM1)
//   g_c1[n]        = (b_align @ W1)[n]
//   g_w2T[n][k]    = bf16( W2[k][n] ), n<128, k<512              (B-operand layout, GEMM2)
__device__ __align__(16) __bf16 g_wcombT[W1C * DIN];
__device__ float g_c1[W1C];
__device__ __align__(16) __bf16 g_w2T[Hd * W1C];

__global__ __launch_bounds__(BLK) void prep_kernel(
    const float* __restrict__ Wa, const float* __restrict__ ba,
    const float* __restrict__ W1, const float* __restrict__ W2)
{
  int i = blockIdx.x * BLK + threadIdx.x;
  if (i < DIN * W1C) {                       // wcombT
    int k = i >> 9, n = i & 511;
    float a = 0.f;
    for (int m = 0; m < Hd; ++m) a += Wa[k*Hd + m] * W1[m*W1C + n];
    g_wcombT[n*DIN + k] = (__bf16)a;
  } else if (i < DIN*W1C + W1C) {            // c1
    int n = i - DIN*W1C;
    float a = 0.f;
    for (int m = 0; m < Hd; ++m) a += ba[m] * W1[m*W1C + n];
    g_c1[n] = a;
  } else if (i < DIN*W1C + W1C + Hd*W1C) {   // w2T
    int j = i - (DIN*W1C + W1C);
    int k = j >> 7, n = j & 127;
    g_w2T[(size_t)n*W1C + k] = (__bf16)W2[k*Hd + n];
  }
}

__device__ __forceinline__ int hword(int f) { return ((f >> 5) * 36) + (f & 31); }

__global__ __launch_bounds__(BLK, 4) void gat_main(
    const float* __restrict__ emb, const int* __restrict__ ei,
    const float* __restrict__ gate_logits,
    const float* __restrict__ a_src1, const float* __restrict__ a_dst1,
    const float* __restrict__ b1,
    const float* __restrict__ a_src2, const float* __restrict__ a_dst2,
    const float* __restrict__ b2,
    const float* __restrict__ Wc1, const float* __restrict__ bc1,
    const float* __restrict__ Wc2, const float* __restrict__ bc2,
    float* __restrict__ out)
{
  __shared__ __align__(16) float hS[Fn * HROW];    // 36864 B; bf16 eluS aliased on top
  __shared__ float alphaS[EPG + Fn];
  __shared__ float sSrc[Fn], sDst[Fn], sInv[Fn], gateS[Fn];
  __shared__ float gpool[Hd], hcS[Fn];
  __shared__ unsigned short colS[EPG + Fn];
  __shared__ unsigned short rowptr[Fn + 1];
  __shared__ unsigned int degS[Fn], cntS[Fn];

  __bf16* eluS = (__bf16*)hS;                      // 64*136*2 = 17408 B <= 36864 B

  const int b    = blockIdx.x;
  const int tid  = threadIdx.x;
  const int lane = tid & 63;
  const int wv   = tid >> 6;
  const int quad = lane >> 4;
  const int l15  = lane & 15;
  const int nodeBase = wv * 16;     // wave owns M-tile: nodes nodeBase..+15
  const int tt   = tid >> 2;        // attention: 4 threads per target node
  const int jj   = tid & 3;

  // ---- gate + CSR build ----
  if (tid < Fn) {
    float g = 1.f / (1.f + expf(-gate_logits[tid]));
    gateS[tid] = g; degS[tid] = 0; cntS[tid] = 0;
    if (b == 0) out[Bg*NC + tid] = g;              // second tuple output
  }
  __syncthreads();
  const int* srcG = ei + (size_t)b * EPG;
  const int* tgtG = ei + (size_t)Etot + (size_t)b * EPG;
  const int base  = b * Fn;
  if (tid < EPG) atomicAdd(&degS[tgtG[tid] - base], 1u);
  else if (tid < EPG + Fn) atomicAdd(&degS[tid - EPG], 1u);
  __syncthreads();
  if (tid == 0) {
    unsigned a = 0;
    for (int i = 0; i < Fn; ++i) { rowptr[i] = (unsigned short)a; a += degS[i]; }
    rowptr[Fn] = (unsigned short)a;
  }
  __syncthreads();
  if (tid < EPG) {
    int s = srcG[tid] - base, t = tgtG[tid] - base;
    colS[rowptr[t] + atomicAdd(&cntS[t], 1u)] = (unsigned short)s;
  } else if (tid < EPG + Fn) {
    int t = tid - EPG;
    colS[rowptr[t] + atomicAdd(&cntS[t], 1u)] = (unsigned short)t;
  }
  __syncthreads();

  const f32x4 zero4 = {0.f, 0.f, 0.f, 0.f};
  f32x4 acc[8];                                    // GEMM2 accumulators (persist over heads)
  #pragma unroll
  for (int i = 0; i < 8; ++i) acc[i] = zero4;

  for (int hh = 0; hh < HEADS; ++hh) {
    // ---- GEMM1 (MFMA, K=32) + fused attention scores ----
    bf16x8 Af;
    {
      const float* ar = emb + ((size_t)base + nodeBase + l15) * DIN + quad * 8;
      float4 e0 = *(const float4*)ar;
      float4 e1 = *(const float4*)(ar + 4);
      Af[0]=(__bf16)e0.x; Af[1]=(__bf16)e0.y; Af[2]=(__bf16)e0.z; Af[3]=(__bf16)e0.w;
      Af[4]=(__bf16)e1.x; Af[5]=(__bf16)e1.y; Af[6]=(__bf16)e1.z; Af[7]=(__bf16)e1.w;
    }
    float ps[4] = {0,0,0,0}, pd[4] = {0,0,0,0};
    float gq[4];
    #pragma unroll
    for (int r = 0; r < 4; ++r) gq[r] = gateS[nodeBase + quad*4 + r];

    #pragma unroll
    for (int Nt = 0; Nt < 8; ++Nt) {
      const int n = Nt*16 + l15;
      bf16x8 Bf = *(const bf16x8*)(g_wcombT + (hh*Hd + n)*DIN + quad*8);
      f32x4 d = __builtin_amdgcn_mfma_f32_16x16x32_bf16(Af, Bf, zero4, 0, 0, 0);
      const float c1v = g_c1[hh*Hd + n];
      const float as  = a_src1[hh*Hd + n];
      const float ad  = a_dst1[hh*Hd + n];
      const int wb = hword(n);
      #pragma unroll
      for (int r = 0; r < 4; ++r) {
        float hv = (d[r] + c1v) * gq[r];
        hS[(nodeBase + quad*4 + r)*HROW + wb] = hv;
        ps[r] += hv * as;
        pd[r] += hv * ad;
      }
    }
    #pragma unroll
    for (int r = 0; r < 4; ++r) {
      #pragma unroll
      for (int off = 1; off < 16; off <<= 1) {
        ps[r] += __shfl_xor(ps[r], off);
        pd[r] += __shfl_xor(pd[r], off);
      }
    }
    if (l15 == 0) {
      #pragma unroll
      for (int r = 0; r < 4; ++r) {
        int m = nodeBase + quad*4 + r;
        sSrc[m] = ps[r]; sDst[m] = pd[r];
      }
    }
    __syncthreads();

    // ---- segment softmax (4 threads per target) ----
    {
      const int r0 = rowptr[tt], r1 = rowptr[tt + 1];
      const float sd = sDst[tt];
      float mx = -1e30f;
      for (int p = r0 + jj; p < r1; p += 4) {
        float e = sSrc[colS[p]] + sd;
        e = (e > 0.f) ? e : 0.2f * e;
        alphaS[p] = e; mx = fmaxf(mx, e);
      }
      mx = fmaxf(mx, __shfl_xor(mx, 1));
      mx = fmaxf(mx, __shfl_xor(mx, 2));
      float ss = 0.f;
      for (int p = r0 + jj; p < r1; p += 4) {
        float pe = __expf(alphaS[p] - mx);
        alphaS[p] = pe; ss += pe;
      }
      ss += __shfl_xor(ss, 1);
      ss += __shfl_xor(ss, 2);
      if (jj == 0) sInv[tt] = 1.f / (ss + 1e-16f);
    }
    __syncthreads();

    // ---- weighted gather (fp32, skewed hS: conflict-free) ----
    float oacc[32];
    #pragma unroll
    for (int i = 0; i < 32; ++i) oacc[i] = 0.f;
    {
      const int r0 = rowptr[tt], r1 = rowptr[tt + 1];
      for (int p = r0; p < r1; ++p) {
        const float al = alphaS[p];
        const float* hr = &hS[(int)colS[p]*HROW + jj*36];
        #pragma unroll
        for (int i = 0; i < 32; i += 4) {
          float4 v = *(const float4*)&hr[i];
          oacc[i]   += al * v.x;
          oacc[i+1] += al * v.y;
          oacc[i+2] += al * v.z;
          oacc[i+3] += al * v.w;
        }
      }
    }
    __syncthreads();                               // all hS reads done

    // ---- +b1, ELU, bf16 -> eluS (aliased over hS) ----
    {
      const float si = sInv[tt];
      const float* bb = b1 + hh*Hd + jj*32;
      __bf16* ew = eluS + tt*EROW + jj*32;
      #pragma unroll
      for (int c = 0; c < 4; ++c) {
        float4 b0 = *(const float4*)&bb[c*8];
        float4 b4 = *(const float4*)&bb[c*8 + 4];
        float v[8];
        v[0]=oacc[c*8+0]*si+b0.x; v[1]=oacc[c*8+1]*si+b0.y;
        v[2]=oacc[c*8+2]*si+b0.z; v[3]=oacc[c*8+3]*si+b0.w;
        v[4]=oacc[c*8+4]*si+b4.x; v[5]=oacc[c*8+5]*si+b4.y;
        v[6]=oacc[c*8+6]*si+b4.z; v[7]=oacc[c*8+7]*si+b4.w;
        bf16x8 w;
        #pragma unroll
        for (int j = 0; j < 8; ++j) {
          float x = v[j];
          x = (x > 0.f) ? x : (__expf(x) - 1.f);
          w[j] = (__bf16)x;
        }
        *(bf16x8*)(ew + c*8) = w;
      }
    }
    __syncthreads();

    // ---- GEMM2 accumulate (MFMA, K=128 this head) ----
    #pragma unroll
    for (int Ks = 0; Ks < 4; ++Ks) {
      bf16x8 A2 = *(const bf16x8*)(eluS + (nodeBase + l15)*EROW + Ks*32 + quad*8);
      #pragma unroll
      for (int Nt = 0; Nt < 8; ++Nt) {
        bf16x8 B2 = *(const bf16x8*)(g_w2T + (size_t)(Nt*16 + l15)*W1C + hh*Hd + Ks*32 + quad*8);
        acc[Nt] = __builtin_amdgcn_mfma_f32_16x16x32_bf16(A2, B2, acc[Nt], 0, 0, 0);
      }
    }
    __syncthreads();                               // eluS reads done before next head's hS writes
  }

  // ---- layer-2: publish h2 + in-register scores ----
  {
    float ps[4] = {0,0,0,0}, pd[4] = {0,0,0,0};
    #pragma unroll
    for (int Nt = 0; Nt < 8; ++Nt) {
      const int n = Nt*16 + l15;
      const float as = a_src2[n], ad = a_dst2[n];
      const int wb = hword(n);
      #pragma unroll
      for (int r = 0; r < 4; ++r) {
        float hv = acc[Nt][r];
        hS[(nodeBase + quad*4 + r)*HROW + wb] = hv;
        ps[r] += hv * as;
        pd[r] += hv * ad;
      }
    }
    #pragma unroll
    for (int r = 0; r < 4; ++r) {
      #pragma unroll
      for (int off = 1; off < 16; off <<= 1) {
        ps[r] += __shfl_xor(ps[r], off);
        pd[r] += __shfl_xor(pd[r], off);
      }
    }
    if (l15 == 0) {
      #pragma unroll
      for (int r = 0; r < 4; ++r) {
        int m = nodeBase + quad*4 + r;
        sSrc[m] = ps[r]; sDst[m] = pd[r];
      }
    }
  }
  __syncthreads();
  {
    const int r0 = rowptr[tt], r1 = rowptr[tt + 1];
    const float sd = sDst[tt];
    float mx = -1e30f;
    for (int p = r0 + jj; p < r1; p += 4) {
      float e = sSrc[colS[p]] + sd;
      e = (e > 0.f) ? e : 0.2f * e;
      alphaS[p] = e; mx = fmaxf(mx, e);
    }
    mx = fmaxf(mx, __shfl_xor(mx, 1));
    mx = fmaxf(mx, __shfl_xor(mx, 2));
    float ss = 0.f;
    for (int p = r0 + jj; p < r1; p += 4) {
      float pe = __expf(alphaS[p] - mx);
      alphaS[p] = pe; ss += pe;
    }
    ss += __shfl_xor(ss, 1);
    ss += __shfl_xor(ss, 2);
    if (jj == 0) sInv[tt] = 1.f / (ss + 1e-16f);
  }
  __syncthreads();
  {
    float oacc[32];
    #pragma unroll
    for (int i = 0; i < 32; ++i) oacc[i] = 0.f;
    const int r0 = rowptr[tt], r1 = rowptr[tt + 1];
    for (int p = r0; p < r1; ++p) {
      const float al = alphaS[p];
      const float* hr = &hS[(int)colS[p]*HROW + jj*36];
      #pragma unroll
      for (int i = 0; i < 32; i += 4) {
        float4 v = *(const float4*)&hr[i];
        oacc[i]   += al * v.x;
        oacc[i+1] += al * v.y;
        oacc[i+2] += al * v.z;
        oacc[i+3] += al * v.w;
      }
    }
    __syncthreads();                               // hS reads done
    const float si = sInv[tt];
    const float* bb = b2 + jj*32;
    float* hw = &hS[tt*HROW + jj*36];
    #pragma unroll
    for (int i = 0; i < 32; i += 4) {
      float4 bv = *(const float4*)&bb[i];
      hw[i]   = oacc[i]  *si + bv.x;
      hw[i+1] = oacc[i+1]*si + bv.y;
      hw[i+2] = oacc[i+2]*si + bv.z;
      hw[i+3] = oacc[i+3]*si + bv.w;
    }
  }
  __syncthreads();

  // ---- global mean pool ----
  if (tid < Hd) {
    const int wf = hword(tid);
    float s = 0.f;
    for (int n = 0; n < Fn; ++n) s += hS[n*HROW + wf];
    gpool[tid] = s * (1.f / 64.f);
  }
  __syncthreads();

  // ---- classifier MLP ----
  if (tid < Fn) {
    float a = bc1[tid];
    for (int k = 0; k < Hd; ++k) a += gpool[k] * Wc1[k*Fn + tid];
    hcS[tid] = a > 0.f ? a : 0.01f * a;
  }
  __syncthreads();
  if (tid < NC) {
    float a = bc2[tid];
    for (int k = 0; k < Fn; ++k) a += hcS[k] * Wc2[k*NC + tid];
    out[b*NC + tid] = a;
  }
}

extern "C" void kernel_launch(void* const* d_in, const int* in_sizes, int n_in,
                              void* d_out, int out_size, void* d_ws, size_t ws_size,
                              hipStream_t stream) {
  const float* emb = (const float*)d_in[0];
  const int*   ei  = (const int*)  d_in[1];
  // d_in[2] = batch_idx (layout known)
  const float* Wa  = (const float*)d_in[3];
  const float* ba  = (const float*)d_in[4];
  const float* gl  = (const float*)d_in[5];
  const float* W1  = (const float*)d_in[6];
  const float* as1 = (const float*)d_in[7];
  const float* ad1 = (const float*)d_in[8];
  const float* b1  = (const float*)d_in[9];
  const float* W2  = (const float*)d_in[10];
  const float* as2 = (const float*)d_in[11];
  const float* ad2 = (const float*)d_in[12];
  const float* b2  = (const float*)d_in[13];
  const float* Wc1 = (const float*)d_in[14];
  const float* bc1 = (const float*)d_in[15];
  const float* Wc2 = (const float*)d_in[16];
  const float* bc2 = (const float*)d_in[17];
  float* out = (float*)d_out;

  const int prepN = DIN*W1C + W1C + Hd*W1C;        // 82432
  hipLaunchKernelGGL(prep_kernel, dim3((prepN + BLK - 1)/BLK), dim3(BLK), 0, stream,
                     Wa, ba, W1, W2);
  hipLaunchKernelGGL(gat_main, dim3(Bg), dim3(BLK), 0, stream,
                     emb, ei, gl, as1, ad1, b1, as2, ad2, b2,
                     Wc1, bc1, Wc2, bc2, out);
}

// Round 3
// 286.682 us; speedup vs baseline: 2.1363x; 1.1987x over previous
//
#include <hip/hip_runtime.h>
#include <math.h>

#define BLK 256

constexpr int Bg    = 2048;
constexpr int Fn    = 64;
constexpr int DIN   = 32;
constexpr int Hd    = 128;
constexpr int HEADS = 4;
constexpr int NC    = 16;
constexpr int EPG   = 128;
constexpr int Etot  = Bg * EPG;
constexpr int W1C   = HEADS * Hd;   // 512
constexpr int NSTR  = 72;           // hT row stride (bf16): 128 feature-rows x 72 nodes
constexpr int EROW  = 136;          // eluS row stride (bf16): 64 node-rows x 136 features
constexpr int PROW  = 72;           // P row stride (bf16): 64 target-rows x 72 sources

typedef __attribute__((ext_vector_type(8))) __bf16 bf16x8;
typedef __attribute__((ext_vector_type(4))) __bf16 bf16x4;
typedef __attribute__((ext_vector_type(4))) float  f32x4;

// Precomputed weights:
//   g_wcombT[n][k] = bf16( (W_align @ W1)[k][n] ), n<512, k<32   (B-operand layout, GEMM1)
//   g_c1[n]        = (b_align @ W1)[n]
//   g_w2T[n][k]    = bf16( W2[k][n] ), n<128, k<512              (B-operand layout, GEMM2)
__device__ __align__(16) __bf16 g_wcombT[W1C * DIN];
__device__ float g_c1[W1C];
__device__ __align__(16) __bf16 g_w2T[Hd * W1C];

__global__ __launch_bounds__(BLK) void prep_kernel(
    const float* __restrict__ Wa, const float* __restrict__ ba,
    const float* __restrict__ W1, const float* __restrict__ W2)
{
  int i = blockIdx.x * BLK + threadIdx.x;
  if (i < DIN * W1C) {                       // wcombT
    int k = i >> 9, n = i & 511;
    float a = 0.f;
    for (int m = 0; m < Hd; ++m) a += Wa[k*Hd + m] * W1[m*W1C + n];
    g_wcombT[n*DIN + k] = (__bf16)a;
  } else if (i < DIN*W1C + W1C) {            // c1
    int n = i - DIN*W1C;
    float a = 0.f;
    for (int m = 0; m < Hd; ++m) a += ba[m] * W1[m*W1C + n];
    g_c1[n] = a;
  } else if (i < DIN*W1C + W1C + Hd*W1C) {   // w2T
    int j = i - (DIN*W1C + W1C);
    int k = j >> 7, n = j & 127;
    g_w2T[(size_t)n*W1C + k] = (__bf16)W2[k*Hd + n];
  }
}

// Per-target softmax over edge list + dense-P build (bf16, RMW handles duplicate
// edges; single owner thread per row -> no atomics needed).
__device__ __forceinline__ void softmax_build_P(
    int tid, __bf16* Psh, const unsigned short* colS, const unsigned short* rowptr,
    const float* sSrc, const float* sDst, float* sInv)
{
  if (tid < Fn) {
    const int t = tid;
    bf16x8 z;
    #pragma unroll
    for (int j = 0; j < 8; ++j) z[j] = (__bf16)0.f;
    #pragma unroll
    for (int i = 0; i < PROW/8; ++i) *(bf16x8*)(Psh + t*PROW + i*8) = z;
    const int r0 = rowptr[t], r1 = rowptr[t+1];
    const float sd = sDst[t];
    float mx = -1e30f;
    for (int p = r0; p < r1; ++p) {
      float e = sSrc[colS[p]] + sd;
      e = (e > 0.f) ? e : 0.2f * e;
      mx = fmaxf(mx, e);
    }
    float ss = 0.f;
    for (int p = r0; p < r1; ++p) {
      float e = sSrc[colS[p]] + sd;
      e = (e > 0.f) ? e : 0.2f * e;
      float pe = __expf(e - mx);
      __bf16* cell = &Psh[t*PROW + colS[p]];
      *cell = (__bf16)((float)*cell + pe);
      ss += pe;
    }
    sInv[t] = 1.f / (ss + 1e-16f);
  }
}

__global__ __launch_bounds__(BLK, 3) void gat_main(
    const float* __restrict__ emb, const int* __restrict__ ei,
    const float* __restrict__ gate_logits,
    const float* __restrict__ a_src1, const float* __restrict__ a_dst1,
    const float* __restrict__ b1,
    const float* __restrict__ a_src2, const float* __restrict__ a_dst2,
    const float* __restrict__ b2,
    const float* __restrict__ Wc1, const float* __restrict__ bc1,
    const float* __restrict__ Wc2, const float* __restrict__ bc2,
    float* __restrict__ out)
{
  __shared__ __align__(16) __bf16 hT[Hd * NSTR];    // 18432 B: h transposed [feature][node]
  __shared__ __align__(16) __bf16 eluS[Fn * EROW];  // 17408 B: elu/out2 [node][feature]
  __shared__ __align__(16) __bf16 Psh[Fn * PROW];   //  9216 B: dense attention [tgt][src]
  __shared__ float sSrc[Fn], sDst[Fn], sInv[Fn], gateS[Fn];
  __shared__ float gpool[Hd], hcS[Fn];
  __shared__ unsigned short colS[EPG + Fn];
  __shared__ unsigned short rowptr[Fn + 1];
  __shared__ unsigned int degS[Fn], cntS[Fn];

  const int b    = blockIdx.x;
  const int tid  = threadIdx.x;
  const int lane = tid & 63;
  const int wv   = tid >> 6;
  const int quad = lane >> 4;
  const int l15  = lane & 15;
  const int nodeBase = wv * 16;     // M-tile of nodes/targets per wave

  // ---- gate + CSR build ----
  if (tid < Fn) {
    float g = 1.f / (1.f + expf(-gate_logits[tid]));
    gateS[tid] = g; degS[tid] = 0; cntS[tid] = 0;
    if (b == 0) out[Bg*NC + tid] = g;               // second tuple output
  }
  __syncthreads();
  const int* srcG = ei + (size_t)b * EPG;
  const int* tgtG = ei + (size_t)Etot + (size_t)b * EPG;
  const int base  = b * Fn;
  if (tid < EPG) atomicAdd(&degS[tgtG[tid] - base], 1u);
  else if (tid < EPG + Fn) atomicAdd(&degS[tid - EPG], 1u);
  __syncthreads();
  if (tid == 0) {
    unsigned a = 0;
    for (int i = 0; i < Fn; ++i) { rowptr[i] = (unsigned short)a; a += degS[i]; }
    rowptr[Fn] = (unsigned short)a;
  }
  __syncthreads();
  if (tid < EPG) {
    int s = srcG[tid] - base, t = tgtG[tid] - base;
    colS[rowptr[t] + atomicAdd(&cntS[t], 1u)] = (unsigned short)s;
  } else if (tid < EPG + Fn) {
    int t = tid - EPG;
    colS[rowptr[t] + atomicAdd(&cntS[t], 1u)] = (unsigned short)t;
  }
  __syncthreads();

  // A-fragment of emb (constant across heads) + gates for this wave's rows
  bf16x8 Af;
  {
    const float* ar = emb + ((size_t)base + nodeBase + l15) * DIN + quad * 8;
    float4 e0 = *(const float4*)ar;
    float4 e1 = *(const float4*)(ar + 4);
    Af[0]=(__bf16)e0.x; Af[1]=(__bf16)e0.y; Af[2]=(__bf16)e0.z; Af[3]=(__bf16)e0.w;
    Af[4]=(__bf16)e1.x; Af[5]=(__bf16)e1.y; Af[6]=(__bf16)e1.z; Af[7]=(__bf16)e1.w;
  }
  float gq[4];
  #pragma unroll
  for (int r = 0; r < 4; ++r) gq[r] = gateS[nodeBase + quad*4 + r];

  const f32x4 zero4 = {0.f, 0.f, 0.f, 0.f};
  f32x4 acc[8];                                     // GEMM2 accumulators
  #pragma unroll
  for (int i = 0; i < 8; ++i) acc[i] = zero4;

  for (int hh = 0; hh < HEADS; ++hh) {
    // ---- A: GEMM1 (MFMA K=32) -> hT (bf16), fused attention scores ----
    {
      float ps[4] = {0,0,0,0}, pd[4] = {0,0,0,0};
      #pragma unroll
      for (int Nt = 0; Nt < 8; ++Nt) {
        const int n = Nt*16 + l15;
        bf16x8 Bf = *(const bf16x8*)(g_wcombT + (hh*Hd + n)*DIN + quad*8);
        f32x4 d = __builtin_amdgcn_mfma_f32_16x16x32_bf16(Af, Bf, zero4, 0, 0, 0);
        const float c1v = g_c1[hh*Hd + n];
        const float as  = a_src1[hh*Hd + n];
        const float ad  = a_dst1[hh*Hd + n];
        bf16x4 hw;
        #pragma unroll
        for (int r = 0; r < 4; ++r) {
          float hv = (d[r] + c1v) * gq[r];
          ps[r] += hv * as;
          pd[r] += hv * ad;
          hw[r] = (__bf16)hv;
        }
        *(bf16x4*)(hT + n*NSTR + nodeBase + quad*4) = hw;
      }
      #pragma unroll
      for (int r = 0; r < 4; ++r) {
        #pragma unroll
        for (int off = 1; off < 16; off <<= 1) {
          ps[r] += __shfl_xor(ps[r], off);
          pd[r] += __shfl_xor(pd[r], off);
        }
      }
      if (l15 == 0) {
        #pragma unroll
        for (int r = 0; r < 4; ++r) {
          int m = nodeBase + quad*4 + r;
          sSrc[m] = ps[r]; sDst[m] = pd[r];
        }
      }
    }
    __syncthreads();

    // ---- B: softmax + dense P ----
    softmax_build_P(tid, Psh, colS, rowptr, sSrc, sDst, sInv);
    __syncthreads();

    // ---- C: aggregation out^T = hT @ P^T (MFMA), epilogue si,b1,ELU -> eluS ----
    {
      const int m0 = wv * 32;
      bf16x8 Ac[2][2];
      #pragma unroll
      for (int Mi = 0; Mi < 2; ++Mi)
        #pragma unroll
        for (int Ks = 0; Ks < 2; ++Ks)
          Ac[Mi][Ks] = *(const bf16x8*)(hT + (m0 + Mi*16 + l15)*NSTR + Ks*32 + quad*8);
      #pragma unroll
      for (int Nt = 0; Nt < 4; ++Nt) {
        bf16x8 B0 = *(const bf16x8*)(Psh + (Nt*16 + l15)*PROW + quad*8);
        bf16x8 B1 = *(const bf16x8*)(Psh + (Nt*16 + l15)*PROW + 32 + quad*8);
        const int t = Nt*16 + l15;
        const float si = sInv[t];
        #pragma unroll
        for (int Mi = 0; Mi < 2; ++Mi) {
          f32x4 d = __builtin_amdgcn_mfma_f32_16x16x32_bf16(Ac[Mi][0], B0, zero4, 0, 0, 0);
          d = __builtin_amdgcn_mfma_f32_16x16x32_bf16(Ac[Mi][1], B1, d, 0, 0, 0);
          const int n0 = m0 + Mi*16 + quad*4;
          bf16x4 w;
          #pragma unroll
          for (int r = 0; r < 4; ++r) {
            float hv = d[r]*si + b1[hh*Hd + n0 + r];
            hv = (hv > 0.f) ? hv : (__expf(hv) - 1.f);
            w[r] = (__bf16)hv;
          }
          *(bf16x4*)(eluS + t*EROW + n0) = w;
        }
      }
    }
    __syncthreads();

    // ---- D: GEMM2 accumulate (MFMA, K=128 this head) ----
    #pragma unroll
    for (int Ks = 0; Ks < 4; ++Ks) {
      bf16x8 A2 = *(const bf16x8*)(eluS + (nodeBase + l15)*EROW + Ks*32 + quad*8);
      #pragma unroll
      for (int Nt = 0; Nt < 8; ++Nt) {
        bf16x8 B2 = *(const bf16x8*)(g_w2T + (size_t)(Nt*16 + l15)*W1C + hh*Hd + Ks*32 + quad*8);
        acc[Nt] = __builtin_amdgcn_mfma_f32_16x16x32_bf16(A2, B2, acc[Nt], 0, 0, 0);
      }
    }
    // no barrier needed: next phase A writes hT, whose readers finished pre-barrier(C)
  }

  // ---- E: publish h2 -> hT (bf16) + layer-2 scores ----
  {
    float ps[4] = {0,0,0,0}, pd[4] = {0,0,0,0};
    #pragma unroll
    for (int Nt = 0; Nt < 8; ++Nt) {
      const int n = Nt*16 + l15;
      const float as = a_src2[n], ad = a_dst2[n];
      bf16x4 hw;
      #pragma unroll
      for (int r = 0; r < 4; ++r) {
        float hv = acc[Nt][r];
        ps[r] += hv * as;
        pd[r] += hv * ad;
        hw[r] = (__bf16)hv;
      }
      *(bf16x4*)(hT + n*NSTR + nodeBase + quad*4) = hw;
    }
    #pragma unroll
    for (int r = 0; r < 4; ++r) {
      #pragma unroll
      for (int off = 1; off < 16; off <<= 1) {
        ps[r] += __shfl_xor(ps[r], off);
        pd[r] += __shfl_xor(pd[r], off);
      }
    }
    if (l15 == 0) {
      #pragma unroll
      for (int r = 0; r < 4; ++r) {
        int m = nodeBase + quad*4 + r;
        sSrc[m] = ps[r]; sDst[m] = pd[r];
      }
    }
  }
  __syncthreads();

  // ---- F: layer-2 softmax + P ----
  softmax_build_P(tid, Psh, colS, rowptr, sSrc, sDst, sInv);
  __syncthreads();

  // ---- G: layer-2 aggregation, epilogue si,b2 (no ELU) -> eluS ----
  {
    const int m0 = wv * 32;
    bf16x8 Ac[2][2];
    #pragma unroll
    for (int Mi = 0; Mi < 2; ++Mi)
      #pragma unroll
      for (int Ks = 0; Ks < 2; ++Ks)
        Ac[Mi][Ks] = *(const bf16x8*)(hT + (m0 + Mi*16 + l15)*NSTR + Ks*32 + quad*8);
    #pragma unroll
    for (int Nt = 0; Nt < 4; ++Nt) {
      bf16x8 B0 = *(const bf16x8*)(Psh + (Nt*16 + l15)*PROW + quad*8);
      bf16x8 B1 = *(const bf16x8*)(Psh + (Nt*16 + l15)*PROW + 32 + quad*8);
      const int t = Nt*16 + l15;
      const float si = sInv[t];
      #pragma unroll
      for (int Mi = 0; Mi < 2; ++Mi) {
        f32x4 d = __builtin_amdgcn_mfma_f32_16x16x32_bf16(Ac[Mi][0], B0, zero4, 0, 0, 0);
        d = __builtin_amdgcn_mfma_f32_16x16x32_bf16(Ac[Mi][1], B1, d, 0, 0, 0);
        const int n0 = m0 + Mi*16 + quad*4;
        bf16x4 w;
        #pragma unroll
        for (int r = 0; r < 4; ++r) {
          float hv = d[r]*si + b2[n0 + r];
          w[r] = (__bf16)hv;
        }
        *(bf16x4*)(eluS + t*EROW + n0) = w;
      }
    }
  }
  __syncthreads();

  // ---- H: global mean pool ----
  if (tid < Hd) {
    float s = 0.f;
    for (int n = 0; n < Fn; ++n) s += (float)eluS[n*EROW + tid];
    gpool[tid] = s * (1.f / 64.f);
  }
  __syncthreads();

  // ---- I: classifier MLP ----
  if (tid < Fn) {
    float a = bc1[tid];
    for (int k = 0; k < Hd; ++k) a += gpool[k] * Wc1[k*Fn + tid];
    hcS[tid] = a > 0.f ? a : 0.01f * a;
  }
  __syncthreads();
  if (tid < NC) {
    float a = bc2[tid];
    for (int k = 0; k < Fn; ++k) a += hcS[k] * Wc2[k*NC + tid];
    out[b*NC + tid] = a;
  }
}

extern "C" void kernel_launch(void* const* d_in, const int* in_sizes, int n_in,
                              void* d_out, int out_size, void* d_ws, size_t ws_size,
                              hipStream_t stream) {
  const float* emb = (const float*)d_in[0];
  const int*   ei  = (const int*)  d_in[1];
  // d_in[2] = batch_idx (layout known)
  const float* Wa  = (const float*)d_in[3];
  const float* ba  = (const float*)d_in[4];
  const float* gl  = (const float*)d_in[5];
  const float* W1  = (const float*)d_in[6];
  const float* as1 = (const float*)d_in[7];
  const float* ad1 = (const float*)d_in[8];
  const float* b1  = (const float*)d_in[9];
  const float* W2  = (const float*)d_in[10];
  const float* as2 = (const float*)d_in[11];
  const float* ad2 = (const float*)d_in[12];
  const float* b2  = (const float*)d_in[13];
  const float* Wc1 = (const float*)d_in[14];
  const float* bc1 = (const float*)d_in[15];
  const float* Wc2 = (const float*)d_in[16];
  const float* bc2 = (const float*)d_in[17];
  float* out = (float*)d_out;

  const int prepN = DIN*W1C + W1C + Hd*W1C;        // 82432
  hipLaunchKernelGGL(prep_kernel, dim3((prepN + BLK - 1)/BLK), dim3(BLK), 0, stream,
                     Wa, ba, W1, W2);
  hipLaunchKernelGGL(gat_main, dim3(Bg), dim3(BLK), 0, stream,
                     emb, ei, gl, as1, ad1, b1, as2, ad2, b2,
                     Wc1, bc1, Wc2, bc2, out);
}